// Round 9
// baseline (515.515 us; speedup 1.0000x reference)
//
#include <hip/hip_runtime.h>
#include <hip/hip_bf16.h>

#define V_ 100000
#define E_ 256
#define H_ 512
#define L_ 50000
#define S_ 512
#define T_ 64
#define NB_ 782        // ceil(L/64)
#define NBP_ 784
#define NWG_ 32
#define NTOT_ 256      // k_lstm grid: 32 LSTM (bid&7==0, co-located XCD) + 224 prefetch

typedef short bf16x8 __attribute__((ext_vector_type(8)));
typedef float f32x4 __attribute__((ext_vector_type(4)));

__device__ __forceinline__ float sigm(float x){ return 1.0f/(1.0f+__expf(-x)); }
__device__ __forceinline__ float tanh_fast(float x){
    x = fminf(fmaxf(x, -15.f), 15.f);
    float e = __expf(2.f * x);
    return __fdividef(e - 1.f, e + 1.f);
}
__device__ __forceinline__ unsigned bf16rne(float x){
    unsigned u = __float_as_uint(x);
    return (u + 0x7fffu + ((u >> 16) & 1u)) >> 16;
}
__device__ __forceinline__ float bcast(float v, int l){
    return __uint_as_float(__builtin_amdgcn_readlane(__float_as_uint(v), l));
}
// L2-homed load: bypass L1 only (sc0), hits the XCD's L2 coherence point.
__device__ __forceinline__ unsigned ld_u32_sc0(const unsigned* p){
    unsigned v;
    asm volatile("global_load_dword %0, %1, off sc0\n\ts_waitcnt vmcnt(0)"
                 : "=v"(v) : "v"(p) : "memory");
    return v;
}

// ---------------- K1: per-step attention (embed -> q -> softmax -> ctx) ----
__global__ __launch_bounds__(256) void k_attn(
    const float* __restrict__ enc, const float* __restrict__ emb,
    const float* __restrict__ W_attn, const float* __restrict__ b_attn,
    const int* __restrict__ word_inputs, float* __restrict__ ctx_out)
{
    __shared__ float e_l[E_];
    __shared__ float q_l[H_];
    __shared__ float sc[S_];
    __shared__ float red[8];
    const int t = blockIdx.x, tid = threadIdx.x;
    const int widx = word_inputs[t];

    e_l[tid] = emb[(long)widx * E_ + tid];
    __syncthreads();

    for (int rr = 0; rr < 2; ++rr) {
        int r = tid + rr * 256;
        const float4* wrow = (const float4*)(W_attn + r * E_);
        const float4* ev = (const float4*)e_l;
        float acc = b_attn[r];
        #pragma unroll 8
        for (int j = 0; j < E_ / 4; ++j) {
            float4 w = wrow[j], e4 = ev[j];
            acc += w.x*e4.x + w.y*e4.y + w.z*e4.z + w.w*e4.w;
        }
        q_l[r] = acc;
    }
    __syncthreads();

    for (int rr = 0; rr < 2; ++rr) {
        int s = tid + rr * 256;
        const float4* er = (const float4*)(enc + s * H_);
        const float4* qv = (const float4*)q_l;
        float acc = 0.f;
        #pragma unroll 8
        for (int j = 0; j < H_ / 4; ++j) {
            float4 a = er[j], b = qv[j];
            acc += a.x*b.x + a.y*b.y + a.z*b.z + a.w*b.w;
        }
        sc[s] = acc;
    }
    __syncthreads();

    float m = fmaxf(sc[tid], sc[tid + 256]);
    for (int off = 32; off; off >>= 1) m = fmaxf(m, __shfl_down(m, off));
    if ((tid & 63) == 0) red[tid >> 6] = m;
    __syncthreads();
    if (tid == 0) red[4] = fmaxf(fmaxf(red[0], red[1]), fmaxf(red[2], red[3]));
    __syncthreads();
    m = red[4];
    float e0 = __expf(sc[tid] - m), e1 = __expf(sc[tid + 256] - m);
    sc[tid] = e0; sc[tid + 256] = e1;
    float ssum = e0 + e1;
    for (int off = 32; off; off >>= 1) ssum += __shfl_down(ssum, off);
    if ((tid & 63) == 0) red[tid >> 6] = ssum;
    __syncthreads();
    if (tid == 0) red[5] = red[0] + red[1] + red[2] + red[3];
    __syncthreads();
    float inv = 1.0f / red[5];

    for (int rr = 0; rr < 2; ++rr) {
        int h = tid + rr * 256;
        float acc = 0.f;
        #pragma unroll 4
        for (int s = 0; s < S_; ++s) acc += sc[s] * enc[s * H_ + h];
        ctx_out[t * H_ + h] = acc * inv;
    }
}

// ---------------- K2: A[t] = W_ih @ ctx_t + b_ih + b_hh ---------------------
__global__ __launch_bounds__(256) void k_gatepre(
    const float* __restrict__ ctx, const float* __restrict__ W_ih,
    const float* __restrict__ b_ih, const float* __restrict__ b_hh,
    float* __restrict__ A_pre)
{
    __shared__ float ctx_t[H_ * 65];   // transposed [k][t], stride 65
    __shared__ float w_l[8 * H_];
    const int tid = threadIdx.x;
    const int r0 = blockIdx.x * 8;

    for (int i = 0; i < 32; ++i) {
        int p = tid + i * 256;
        int t = p >> 7, k4 = p & 127;
        float4 v = ((const float4*)ctx)[p];
        ctx_t[(k4*4+0)*65 + t] = v.x;
        ctx_t[(k4*4+1)*65 + t] = v.y;
        ctx_t[(k4*4+2)*65 + t] = v.z;
        ctx_t[(k4*4+3)*65 + t] = v.w;
    }
    for (int i = 0; i < 4; ++i) {
        int p = tid + i * 256;
        int row = p >> 7, k4 = p & 127;
        float4 v = ((const float4*)W_ih)[(r0 + row) * (H_/4) + k4];
        float* dst = &w_l[row * H_ + k4 * 4];
        dst[0]=v.x; dst[1]=v.y; dst[2]=v.z; dst[3]=v.w;
    }
    __syncthreads();

    const int t = tid & 63, half = tid >> 6;
    const float* w0 = &w_l[(half*2+0) * H_];
    const float* w1 = &w_l[(half*2+1) * H_];
    float acc0 = 0.f, acc1 = 0.f;
    #pragma unroll 4
    for (int k = 0; k < H_; ++k) {
        float cv = ctx_t[k * 65 + t];
        acc0 += w0[k] * cv;
        acc1 += w1[k] * cv;
    }
    int ra = r0 + half * 2, rb = ra + 1;
    A_pre[t * 2048 + ra] = acc0 + b_ih[ra] + b_hh[ra];
    A_pre[t * 2048 + rb] = acc1 + b_ih[rb] + b_hh[rb];
}

// ---------------- K3: persistent LSTM, L2-homed sync on ONE XCD -------------
// 256 WGs; bid&7==0 -> LSTM role (all on XCD0 under bid%8 round-robin),
// else -> W_out L3-prefetch. LSTM: 8 waves/WG, wave = 64-k slice, lane polls
// ONE h value via sc0 (XCD-L2); producers dual-store (plain L2 + agent LLC);
// consumers fall back to the LLC buffer after 32 spins -> correct under ANY
// workgroup->XCD mapping, fast under the expected one. W in AGPRs.
#define ST(i, val) asm volatile("v_accvgpr_write_b32 %0, %1" : "=a"(g##i) : "v"(val));
#define STQ(q,i0,i1,i2,i3) { float4 v_ = wsrc[q]; ST(i0,v_.x) ST(i1,v_.y) ST(i2,v_.z) ST(i3,v_.w) }
#define MAC4(i0,i1,i2,i3) { float w0_,w1_,w2_,w3_; \
  asm volatile("v_accvgpr_read_b32 %0, %1" : "=v"(w0_) : "a"(g##i0)); \
  asm volatile("v_accvgpr_read_b32 %0, %1" : "=v"(w1_) : "a"(g##i1)); \
  asm volatile("v_accvgpr_read_b32 %0, %1" : "=v"(w2_) : "a"(g##i2)); \
  asm volatile("v_accvgpr_read_b32 %0, %1" : "=v"(w3_) : "a"(g##i3)); \
  a0 += w0_ * bcast(hv, i0); a1 += w1_ * bcast(hv, i1); \
  a2 += w2_ * bcast(hv, i2); a3 += w3_ * bcast(hv, i3); }

__global__ __launch_bounds__(512, 1) void k_lstm(
    const float* __restrict__ W_hh, const float* __restrict__ A_pre,
    const float* __restrict__ h0, const float* __restrict__ c0,
    float* __restrict__ h_buf, float* __restrict__ h_slow,
    const float* __restrict__ W_out)
{
    const int tid = threadIdx.x, bid = blockIdx.x;

    if ((bid & 7) != 0) {
        // ---- W_out L3 warm on non-LSTM XCDs: 224 WGs stream 102 MB ----
        const int pfid = bid - (bid >> 3) - 1;              // [0, 224)
        const long total = (long)L_ * H_ / 4;               // float4 count
        const long stride = (long)224 * 512;
        const float4* src = (const float4*)W_out;
        float acc = 0.f;
        for (long i = (long)pfid * 512 + tid; i < total; i += stride) {
            float4 v = src[i];
            acc += v.x + v.y + v.z + v.w;
        }
        asm volatile("" :: "v"(acc));
        return;
    }
    const int wg = bid >> 3;            // LSTM workgroup id [0, 32)

    __shared__ float A_l[T_ * 64];      // [t][r]
    __shared__ float red[2][8][64];     // [parity][ks][r]

    const int base = wg * 16;
    const int lane = tid & 63;
    const int ks   = tid >> 6;
    const int G = ((lane >> 4) << 9) + base + (lane & 15);  // global gate row

    // ---- W slice -> 64 AGPRs ----
    float g0,g1,g2,g3,g4,g5,g6,g7,g8,g9,g10,g11,g12,g13,g14,g15;
    float g16,g17,g18,g19,g20,g21,g22,g23,g24,g25,g26,g27,g28,g29,g30,g31;
    float g32,g33,g34,g35,g36,g37,g38,g39,g40,g41,g42,g43,g44,g45,g46,g47;
    float g48,g49,g50,g51,g52,g53,g54,g55,g56,g57,g58,g59,g60,g61,g62,g63;
    {
        const float4* wsrc = (const float4*)(W_hh + (long)G * H_ + ks * 64);
        STQ(0,0,1,2,3)     STQ(1,4,5,6,7)     STQ(2,8,9,10,11)   STQ(3,12,13,14,15)
        STQ(4,16,17,18,19) STQ(5,20,21,22,23) STQ(6,24,25,26,27) STQ(7,28,29,30,31)
        STQ(8,32,33,34,35) STQ(9,36,37,38,39) STQ(10,40,41,42,43)STQ(11,44,45,46,47)
        STQ(12,48,49,50,51)STQ(13,52,53,54,55)STQ(14,56,57,58,59)STQ(15,60,61,62,63)
    }

    // A_pre slice -> LDS (off critical path)
    for (int i = 0; i < 8; ++i) {
        int p = tid + i * 512;          // [0, 4096)
        int tt = p >> 6, rr = p & 63;
        A_l[p] = A_pre[tt * 2048 + ((rr >> 4) << 9) + base + (rr & 15)];
    }
    float c_reg = 0.f;
    if (tid < 16) c_reg = c0[base + tid];
    __syncthreads();

    const unsigned SENT = 0xFFFFFFFFu;

    for (int t = 0; t < T_; ++t) {
        // ---- acquire this wave's 64 h values (1 poll per lane, L2-homed) ---
        float hv;
        if (t == 0) {
            hv = h0[ks * 64 + lane];
        } else {
            const unsigned* fb = (const unsigned*)h_buf  + (t - 1) * H_ + ks * 64 + lane;
            const unsigned* sb = (const unsigned*)h_slow + (t - 1) * H_ + ks * 64 + lane;
            unsigned u = ld_u32_sc0(fb);
            int spins = 0;
            while (u == SENT) {
                __builtin_amdgcn_s_sleep(1);
                u = ld_u32_sc0(fb);
                if (u == SENT && ++spins > 32)
                    u = __hip_atomic_load(sb, __ATOMIC_RELAXED,
                                          __HIP_MEMORY_SCOPE_AGENT);
            }
            hv = __uint_as_float(u);
        }

        // ---- partial dot over this wave's 64-k slice (W from AGPRs) ----
        float a0 = 0.f, a1 = 0.f, a2 = 0.f, a3 = 0.f;
        MAC4(0,1,2,3)     MAC4(4,5,6,7)     MAC4(8,9,10,11)   MAC4(12,13,14,15)
        MAC4(16,17,18,19) MAC4(20,21,22,23) MAC4(24,25,26,27) MAC4(28,29,30,31)
        MAC4(32,33,34,35) MAC4(36,37,38,39) MAC4(40,41,42,43) MAC4(44,45,46,47)
        MAC4(48,49,50,51) MAC4(52,53,54,55) MAC4(56,57,58,59) MAC4(60,61,62,63)
        red[t & 1][ks][lane] = (a0 + a1) + (a2 + a3);
        __syncthreads();

        // ---- wave 0 finalizes: sum 8 partials, gather gates, nonlinearity --
        if (ks == 0) {
            float s = A_l[t * 64 + lane];
            #pragma unroll
            for (int k2 = 0; k2 < 8; ++k2) s += red[t & 1][k2][lane];
            float gf_ = __shfl_down(s, 16);
            float gg_ = __shfl_down(s, 32);
            float go_ = __shfl_down(s, 48);
            if (lane < 16) {
                float gi = sigm(s);
                float gf = sigm(gf_);
                float gg = tanh_fast(gg_);
                float go = sigm(go_);
                float c2 = gf * c_reg + gi * gg;
                c_reg = c2;
                float h2 = go * tanh_fast(c2);
                unsigned hbits = __float_as_uint(h2);
                // fast: plain store -> write-through L1 -> XCD-L2 (coherence pt)
                *(volatile unsigned*)((unsigned*)h_buf + t * H_ + base + lane) = hbits;
                // slow: agent store -> LLC (fallback for misplaced consumers)
                __hip_atomic_store((unsigned*)h_slow + t * H_ + base + lane, hbits,
                                   __ATOMIC_RELAXED, __HIP_MEMORY_SCOPE_AGENT);
            }
        }
        // no trailing barrier: red is parity double-buffered
    }
}

// ---------------- K4: MFMA W_out GEMM + per-block softmax partials ----------
__global__ __launch_bounds__(256) void k_out(
    const float* __restrict__ W_out, const float* __restrict__ b_out,
    const float* __restrict__ h_buf, const int* __restrict__ labels,
    float* __restrict__ pm, float* __restrict__ ps, float* __restrict__ ll)
{
    __shared__ __align__(16) unsigned char smem[65536];
    const int tid = threadIdx.x;
    const int r0 = blockIdx.x * 64;
    const int lane = tid & 63, w = tid >> 6;
    const int g = lane >> 4, li = lane & 15;

    // ---- stage h -> bf16 LDS [t][k], byte = (t*1024 + k*2) ^ ((t&7)<<4) ----
    for (int i = 0; i < 32; ++i) {
        int p = tid + i * 256;           // float4 idx over [64][128]
        int t = p >> 7, k4 = p & 127;
        float4 v = ((const float4*)h_buf)[p];
        unsigned p01 = bf16rne(v.x) | (bf16rne(v.y) << 16);
        unsigned p23 = bf16rne(v.z) | (bf16rne(v.w) << 16);
        unsigned byte = (unsigned)(t * 1024 + k4 * 8) ^ ((unsigned)(t & 7) << 4);
        *(uint2*)(smem + byte) = make_uint2(p01, p23);
    }

    f32x4 acc0 = {0.f,0.f,0.f,0.f}, acc1 = {0.f,0.f,0.f,0.f};
    f32x4 acc2 = {0.f,0.f,0.f,0.f}, acc3 = {0.f,0.f,0.f,0.f};
    __syncthreads();

    int rrow = r0 + w * 16 + li;
    int rw = rrow < L_ ? rrow : (L_ - 1);
    const float* ap = W_out + (long)rw * H_ + g * 8;

    #pragma unroll
    for (int kk = 0; kk < 16; ++kk) {
        float4 va = *(const float4*)(ap + kk * 32);
        float4 vb = *(const float4*)(ap + kk * 32 + 4);
        union { unsigned u[4]; bf16x8 v; } A;
        A.u[0] = bf16rne(va.x) | (bf16rne(va.y) << 16);
        A.u[1] = bf16rne(va.z) | (bf16rne(va.w) << 16);
        A.u[2] = bf16rne(vb.x) | (bf16rne(vb.y) << 16);
        A.u[3] = bf16rne(vb.z) | (bf16rne(vb.w) << 16);

        #pragma unroll
        for (int nt = 0; nt < 4; ++nt) {
            int t = nt * 16 + li;
            unsigned byte = (unsigned)(t * 1024 + kk * 64 + g * 16)
                          ^ ((unsigned)(t & 7) << 4);
            bf16x8 B = *(const bf16x8*)(smem + byte);
            f32x4* accp = (nt == 0) ? &acc0 : (nt == 1) ? &acc1
                        : (nt == 2) ? &acc2 : &acc3;
            *accp = __builtin_amdgcn_mfma_f32_16x16x32_bf16(A.v, B, *accp, 0, 0, 0);
        }
    }
    __syncthreads();

    float* lg   = (float*)smem;
    float* redb = (float*)(smem + 64 * 65 * 4);
    float* gmax = redb + 256;

    #pragma unroll
    for (int nt = 0; nt < 4; ++nt) {
        const f32x4 a = (nt == 0) ? acc0 : (nt == 1) ? acc1
                      : (nt == 2) ? acc2 : acc3;
        int t = nt * 16 + li;
        #pragma unroll
        for (int q = 0; q < 4; ++q) {
            int rloc = w * 16 + g * 4 + q;
            int r = r0 + rloc;
            float v = -1e30f;
            if (r < L_) v = a[q] + b_out[r];
            lg[rloc * 65 + t] = v;
        }
    }
    __syncthreads();

    const int t = tid & 63, part = tid >> 6;
    float m = -1e30f;
    #pragma unroll
    for (int r16 = 0; r16 < 16; ++r16)
        m = fmaxf(m, lg[(part*16 + r16)*65 + t]);
    redb[part*64 + t] = m;
    __syncthreads();
    if (part == 0)
        gmax[t] = fmaxf(fmaxf(redb[t], redb[64+t]), fmaxf(redb[128+t], redb[192+t]));
    __syncthreads();
    float gm = gmax[t];
    float s = 0.f;
    #pragma unroll
    for (int r16 = 0; r16 < 16; ++r16)
        s += __expf(lg[(part*16 + r16)*65 + t] - gm);
    __syncthreads();
    redb[part*64 + t] = s;
    __syncthreads();
    if (part == 0) {
        pm[t * NBP_ + blockIdx.x] = gm;
        ps[t * NBP_ + blockIdx.x] = redb[t] + redb[64+t] + redb[128+t] + redb[192+t];
        int lb = labels[t];
        if (lb >= r0 && lb < r0 + 64) ll[t] = lg[(lb - r0)*65 + t];
    }
}

// ---------------- K5: combine partials, NLL, total loss ---------------------
__global__ __launch_bounds__(256) void k_final(
    const float* __restrict__ pm, const float* __restrict__ ps,
    const float* __restrict__ ll, const int* __restrict__ labels,
    float* __restrict__ out)
{
    __shared__ float rbuf[8];
    const int t = blockIdx.x, tid = threadIdx.x;
    float m = -1e30f;
    for (int b = tid; b < NB_; b += 256) m = fmaxf(m, pm[t * NBP_ + b]);
    for (int off = 32; off; off >>= 1) m = fmaxf(m, __shfl_down(m, off));
    if ((tid & 63) == 0) rbuf[tid >> 6] = m;
    __syncthreads();
    if (tid == 0) rbuf[4] = fmaxf(fmaxf(rbuf[0], rbuf[1]), fmaxf(rbuf[2], rbuf[3]));
    __syncthreads();
    float M = rbuf[4];
    __syncthreads();
    float s = 0.f;
    for (int b = tid; b < NB_; b += 256)
        s += ps[t * NBP_ + b] * __expf(pm[t * NBP_ + b] - M);
    for (int off = 32; off; off >>= 1) s += __shfl_down(s, off);
    if ((tid & 63) == 0) rbuf[tid >> 6] = s;
    __syncthreads();
    if (tid == 0) {
        float S = rbuf[0] + rbuf[1] + rbuf[2] + rbuf[3];
        int lb = labels[t];
        if (lb != 0) {
            float loss = -(ll[t] - M - __logf(S));
            atomicAdd(out, loss);
        }
    }
}

extern "C" void kernel_launch(void* const* d_in, const int* in_sizes, int n_in,
                              void* d_out, int out_size, void* d_ws, size_t ws_size,
                              hipStream_t stream)
{
    (void)in_sizes; (void)n_in; (void)out_size; (void)ws_size;
    const float* enc    = (const float*)d_in[0];
    const float* h0     = (const float*)d_in[1];
    const float* c0     = (const float*)d_in[2];
    const float* emb    = (const float*)d_in[3];
    const float* W_attn = (const float*)d_in[4];
    const float* b_attn = (const float*)d_in[5];
    const float* W_ih   = (const float*)d_in[6];
    const float* W_hh   = (const float*)d_in[7];
    const float* b_ih   = (const float*)d_in[8];
    const float* b_hh   = (const float*)d_in[9];
    const float* W_out  = (const float*)d_in[10];
    const float* b_out  = (const float*)d_in[11];
    const int* widx     = (const int*)d_in[12];
    const int* labels   = (const int*)d_in[13];
    float* out = (float*)d_out;

    char* ws = (char*)d_ws;
    float* ctx    = (float*)(ws + 0);          // 64*512*4      = 131072
    float* A_pre  = (float*)(ws + 131072);     // 64*2048*4     = 524288
    float* h_buf  = (float*)(ws + 655360);     // 64*512*4      = 131072
    float* pm     = (float*)(ws + 786688);     // 64*784*4      = 200704
    float* ps     = (float*)(ws + 987392);     // 64*784*4      = 200704
    float* ll     = (float*)(ws + 1188096);    // 64*4 (pad to 256)
    float* h_slow = (float*)(ws + 1188352);    // 64*512*4      = 131072

    hipMemsetAsync(h_buf,  0xFF, T_ * H_ * sizeof(float), stream);  // sentinel
    hipMemsetAsync(h_slow, 0xFF, T_ * H_ * sizeof(float), stream);  // sentinel
    hipMemsetAsync(out, 0, sizeof(float), stream);

    k_attn<<<T_, 256, 0, stream>>>(enc, emb, W_attn, b_attn, widx, ctx);
    k_gatepre<<<256, 256, 0, stream>>>(ctx, W_ih, b_ih, b_hh, A_pre);
    k_lstm<<<NTOT_, 512, 0, stream>>>(W_hh, A_pre, h0, c0, h_buf, h_slow, W_out);
    k_out<<<NB_, 256, 0, stream>>>(W_out, b_out, h_buf, labels, pm, ps, ll);
    k_final<<<T_, 256, 0, stream>>>(pm, ps, ll, labels, out);
}

// Round 11
// 240.122 us; speedup vs baseline: 2.1469x; 2.1469x over previous
//
#include <hip/hip_runtime.h>
#include <hip/hip_bf16.h>

#define V_ 100000
#define E_ 256
#define H_ 512
#define L_ 50000
#define S_ 512
#define T_ 64
#define NB_ 782        // ceil(L/64)
#define NBP_ 784
#define NWG_ 32

typedef short bf16x8 __attribute__((ext_vector_type(8)));
typedef float f32x4 __attribute__((ext_vector_type(4)));

__device__ __forceinline__ float sigm(float x){ return 1.0f/(1.0f+__expf(-x)); }
__device__ __forceinline__ float tanh_fast(float x){
    x = fminf(fmaxf(x, -15.f), 15.f);
    float e = __expf(2.f * x);
    return __fdividef(e - 1.f, e + 1.f);
}
__device__ __forceinline__ unsigned bf16rne(float x){
    unsigned u = __float_as_uint(x);
    return (u + 0x7fffu + ((u >> 16) & 1u)) >> 16;
}
__device__ __forceinline__ float bcast(float v, int l){
    return __uint_as_float(__builtin_amdgcn_readlane(__float_as_uint(v), l));
}

// ---------------- K1: per-step attention (embed -> q -> softmax -> ctx) ----
__global__ __launch_bounds__(256) void k_attn(
    const float* __restrict__ enc, const float* __restrict__ emb,
    const float* __restrict__ W_attn, const float* __restrict__ b_attn,
    const int* __restrict__ word_inputs, float* __restrict__ ctx_out)
{
    __shared__ float e_l[E_];
    __shared__ float q_l[H_];
    __shared__ float sc[S_];
    __shared__ float red[8];
    const int t = blockIdx.x, tid = threadIdx.x;
    const int widx = word_inputs[t];

    e_l[tid] = emb[(long)widx * E_ + tid];
    __syncthreads();

    for (int rr = 0; rr < 2; ++rr) {
        int r = tid + rr * 256;
        const float4* wrow = (const float4*)(W_attn + r * E_);
        const float4* ev = (const float4*)e_l;
        float acc = b_attn[r];
        #pragma unroll 8
        for (int j = 0; j < E_ / 4; ++j) {
            float4 w = wrow[j], e4 = ev[j];
            acc += w.x*e4.x + w.y*e4.y + w.z*e4.z + w.w*e4.w;
        }
        q_l[r] = acc;
    }
    __syncthreads();

    for (int rr = 0; rr < 2; ++rr) {
        int s = tid + rr * 256;
        const float4* er = (const float4*)(enc + s * H_);
        const float4* qv = (const float4*)q_l;
        float acc = 0.f;
        #pragma unroll 8
        for (int j = 0; j < H_ / 4; ++j) {
            float4 a = er[j], b = qv[j];
            acc += a.x*b.x + a.y*b.y + a.z*b.z + a.w*b.w;
        }
        sc[s] = acc;
    }
    __syncthreads();

    float m = fmaxf(sc[tid], sc[tid + 256]);
    for (int off = 32; off; off >>= 1) m = fmaxf(m, __shfl_down(m, off));
    if ((tid & 63) == 0) red[tid >> 6] = m;
    __syncthreads();
    if (tid == 0) red[4] = fmaxf(fmaxf(red[0], red[1]), fmaxf(red[2], red[3]));
    __syncthreads();
    m = red[4];
    float e0 = __expf(sc[tid] - m), e1 = __expf(sc[tid + 256] - m);
    sc[tid] = e0; sc[tid + 256] = e1;
    float ssum = e0 + e1;
    for (int off = 32; off; off >>= 1) ssum += __shfl_down(ssum, off);
    if ((tid & 63) == 0) red[tid >> 6] = ssum;
    __syncthreads();
    if (tid == 0) red[5] = red[0] + red[1] + red[2] + red[3];
    __syncthreads();
    float inv = 1.0f / red[5];

    for (int rr = 0; rr < 2; ++rr) {
        int h = tid + rr * 256;
        float acc = 0.f;
        #pragma unroll 4
        for (int s = 0; s < S_; ++s) acc += sc[s] * enc[s * H_ + h];
        ctx_out[t * H_ + h] = acc * inv;
    }
}

// ---------------- K2: A[t] = W_ih @ ctx_t + b_ih + b_hh ---------------------
__global__ __launch_bounds__(256) void k_gatepre(
    const float* __restrict__ ctx, const float* __restrict__ W_ih,
    const float* __restrict__ b_ih, const float* __restrict__ b_hh,
    float* __restrict__ A_pre)
{
    __shared__ float ctx_t[H_ * 65];   // transposed [k][t], stride 65
    __shared__ float w_l[8 * H_];
    const int tid = threadIdx.x;
    const int r0 = blockIdx.x * 8;

    for (int i = 0; i < 32; ++i) {
        int p = tid + i * 256;
        int t = p >> 7, k4 = p & 127;
        float4 v = ((const float4*)ctx)[p];
        ctx_t[(k4*4+0)*65 + t] = v.x;
        ctx_t[(k4*4+1)*65 + t] = v.y;
        ctx_t[(k4*4+2)*65 + t] = v.z;
        ctx_t[(k4*4+3)*65 + t] = v.w;
    }
    for (int i = 0; i < 4; ++i) {
        int p = tid + i * 256;
        int row = p >> 7, k4 = p & 127;
        float4 v = ((const float4*)W_ih)[(r0 + row) * (H_/4) + k4];
        float* dst = &w_l[row * H_ + k4 * 4];
        dst[0]=v.x; dst[1]=v.y; dst[2]=v.z; dst[3]=v.w;
    }
    __syncthreads();

    const int t = tid & 63, half = tid >> 6;
    const float* w0 = &w_l[(half*2+0) * H_];
    const float* w1 = &w_l[(half*2+1) * H_];
    float acc0 = 0.f, acc1 = 0.f;
    #pragma unroll 4
    for (int k = 0; k < H_; ++k) {
        float cv = ctx_t[k * 65 + t];
        acc0 += w0[k] * cv;
        acc1 += w1[k] * cv;
    }
    int ra = r0 + half * 2, rb = ra + 1;
    A_pre[t * 2048 + ra] = acc0 + b_ih[ra] + b_hh[ra];
    A_pre[t * 2048 + rb] = acc1 + b_ih[rb] + b_hh[rb];
}

// ---------------- K3: persistent LSTM (32 WGs, W in AGPRs, pre-poll read) ---
// 8 waves/WG, wave = 64-k slice, lane polls ONE h value.
// Per step: AGPR->VGPR W reads FIRST (independent of h, pinned by
// sched_barrier), then poll, then 64 readlane+FMA, then R4 reduce tail.
#define ST(i, val) asm volatile("v_accvgpr_write_b32 %0, %1" : "=a"(g##i) : "v"(val));
#define STQ(q,i0,i1,i2,i3) { float4 v_ = wsrc[q]; ST(i0,v_.x) ST(i1,v_.y) ST(i2,v_.z) ST(i3,v_.w) }
#define RD1(i) float wv##i; asm volatile("v_accvgpr_read_b32 %0, %1" : "=v"(wv##i) : "a"(g##i));
#define RD4(i0,i1,i2,i3) RD1(i0) RD1(i1) RD1(i2) RD1(i3)
#define FMA4(i0,i1,i2,i3) \
    a0 += wv##i0 * bcast(hv, i0); a1 += wv##i1 * bcast(hv, i1); \
    a2 += wv##i2 * bcast(hv, i2); a3 += wv##i3 * bcast(hv, i3);

__global__ __launch_bounds__(512, 1) void k_lstm(
    const float* __restrict__ W_hh, const float* __restrict__ A_pre,
    const float* __restrict__ h0, const float* __restrict__ c0,
    float* __restrict__ h_buf)
{
    const int tid = threadIdx.x, wg = blockIdx.x;

    __shared__ float A_l[T_ * 64];      // [t][r]
    __shared__ float red[2][8][64];     // [parity][ks][r]

    const int base = wg * 16;
    const int lane = tid & 63;
    const int ks   = tid >> 6;
    const int G = ((lane >> 4) << 9) + base + (lane & 15);  // global gate row

    // ---- W slice -> 64 AGPRs ----
    float g0,g1,g2,g3,g4,g5,g6,g7,g8,g9,g10,g11,g12,g13,g14,g15;
    float g16,g17,g18,g19,g20,g21,g22,g23,g24,g25,g26,g27,g28,g29,g30,g31;
    float g32,g33,g34,g35,g36,g37,g38,g39,g40,g41,g42,g43,g44,g45,g46,g47;
    float g48,g49,g50,g51,g52,g53,g54,g55,g56,g57,g58,g59,g60,g61,g62,g63;
    {
        const float4* wsrc = (const float4*)(W_hh + (long)G * H_ + ks * 64);
        STQ(0,0,1,2,3)     STQ(1,4,5,6,7)     STQ(2,8,9,10,11)   STQ(3,12,13,14,15)
        STQ(4,16,17,18,19) STQ(5,20,21,22,23) STQ(6,24,25,26,27) STQ(7,28,29,30,31)
        STQ(8,32,33,34,35) STQ(9,36,37,38,39) STQ(10,40,41,42,43)STQ(11,44,45,46,47)
        STQ(12,48,49,50,51)STQ(13,52,53,54,55)STQ(14,56,57,58,59)STQ(15,60,61,62,63)
    }

    // A_pre slice -> LDS (off critical path)
    for (int i = 0; i < 8; ++i) {
        int p = tid + i * 512;          // [0, 4096)
        int tt = p >> 6, rr = p & 63;
        A_l[p] = A_pre[tt * 2048 + ((rr >> 4) << 9) + base + (rr & 15)];
    }
    float c_reg = 0.f;
    if (tid < 16) c_reg = c0[base + tid];
    __syncthreads();

    const unsigned SENT = 0xFFFFFFFFu;

    for (int t = 0; t < T_; ++t) {
        // ---- (1) W: AGPR -> VGPR, independent of h; pinned before the poll -
        RD4(0,1,2,3)     RD4(4,5,6,7)     RD4(8,9,10,11)   RD4(12,13,14,15)
        RD4(16,17,18,19) RD4(20,21,22,23) RD4(24,25,26,27) RD4(28,29,30,31)
        RD4(32,33,34,35) RD4(36,37,38,39) RD4(40,41,42,43) RD4(44,45,46,47)
        RD4(48,49,50,51) RD4(52,53,54,55) RD4(56,57,58,59) RD4(60,61,62,63)
        __builtin_amdgcn_sched_barrier(0);

        // ---- (2) acquire this wave's 64 h values (1 poll load per lane) ----
        float hv;
        if (t == 0) {
            hv = h0[ks * 64 + lane];
        } else {
            const unsigned* hb = (const unsigned*)h_buf + (t - 1) * H_ + ks * 64;
            unsigned u = __hip_atomic_load(hb + lane, __ATOMIC_RELAXED,
                                           __HIP_MEMORY_SCOPE_AGENT);
            while (u == SENT) {
                __builtin_amdgcn_s_sleep(1);
                u = __hip_atomic_load(hb + lane, __ATOMIC_RELAXED,
                                      __HIP_MEMORY_SCOPE_AGENT);
            }
            hv = __uint_as_float(u);
        }

        // ---- (3) partial dot over this wave's 64-k slice ----
        float a0 = 0.f, a1 = 0.f, a2 = 0.f, a3 = 0.f;
        FMA4(0,1,2,3)     FMA4(4,5,6,7)     FMA4(8,9,10,11)   FMA4(12,13,14,15)
        FMA4(16,17,18,19) FMA4(20,21,22,23) FMA4(24,25,26,27) FMA4(28,29,30,31)
        FMA4(32,33,34,35) FMA4(36,37,38,39) FMA4(40,41,42,43) FMA4(44,45,46,47)
        FMA4(48,49,50,51) FMA4(52,53,54,55) FMA4(56,57,58,59) FMA4(60,61,62,63)
        red[t & 1][ks][lane] = (a0 + a1) + (a2 + a3);
        __syncthreads();

        // ---- (4) wave 0 finalizes: sum partials, gather gates, nonlinearity
        if (ks == 0) {
            float s = A_l[t * 64 + lane];
            #pragma unroll
            for (int k2 = 0; k2 < 8; ++k2) s += red[t & 1][k2][lane];
            float gf_ = __shfl_down(s, 16);
            float gg_ = __shfl_down(s, 32);
            float go_ = __shfl_down(s, 48);
            if (lane < 16) {
                float gi = sigm(s);
                float gf = sigm(gf_);
                float gg = tanh_fast(gg_);
                float go = sigm(go_);
                float c2 = gf * c_reg + gi * gg;
                c_reg = c2;
                float h2 = go * tanh_fast(c2);
                __hip_atomic_store((unsigned*)h_buf + t * H_ + base + lane,
                                   __float_as_uint(h2),
                                   __ATOMIC_RELAXED, __HIP_MEMORY_SCOPE_AGENT);
            }
        }
        // no trailing barrier: red is parity double-buffered
    }
}

// ---------------- K4: MFMA W_out GEMM + per-block softmax partials ----------
__global__ __launch_bounds__(256) void k_out(
    const float* __restrict__ W_out, const float* __restrict__ b_out,
    const float* __restrict__ h_buf, const int* __restrict__ labels,
    float* __restrict__ pm, float* __restrict__ ps, float* __restrict__ ll)
{
    __shared__ __align__(16) unsigned char smem[65536];
    const int tid = threadIdx.x;
    const int r0 = blockIdx.x * 64;
    const int lane = tid & 63, w = tid >> 6;
    const int g = lane >> 4, li = lane & 15;

    // ---- stage h -> bf16 LDS [t][k], byte = (t*1024 + k*2) ^ ((t&7)<<4) ----
    for (int i = 0; i < 32; ++i) {
        int p = tid + i * 256;           // float4 idx over [64][128]
        int t = p >> 7, k4 = p & 127;
        float4 v = ((const float4*)h_buf)[p];
        unsigned p01 = bf16rne(v.x) | (bf16rne(v.y) << 16);
        unsigned p23 = bf16rne(v.z) | (bf16rne(v.w) << 16);
        unsigned byte = (unsigned)(t * 1024 + k4 * 8) ^ ((unsigned)(t & 7) << 4);
        *(uint2*)(smem + byte) = make_uint2(p01, p23);
    }

    f32x4 acc0 = {0.f,0.f,0.f,0.f}, acc1 = {0.f,0.f,0.f,0.f};
    f32x4 acc2 = {0.f,0.f,0.f,0.f}, acc3 = {0.f,0.f,0.f,0.f};
    __syncthreads();

    int rrow = r0 + w * 16 + li;
    int rw = rrow < L_ ? rrow : (L_ - 1);
    const float* ap = W_out + (long)rw * H_ + g * 8;

    #pragma unroll
    for (int kk = 0; kk < 16; ++kk) {
        float4 va = *(const float4*)(ap + kk * 32);
        float4 vb = *(const float4*)(ap + kk * 32 + 4);
        union { unsigned u[4]; bf16x8 v; } A;
        A.u[0] = bf16rne(va.x) | (bf16rne(va.y) << 16);
        A.u[1] = bf16rne(va.z) | (bf16rne(va.w) << 16);
        A.u[2] = bf16rne(vb.x) | (bf16rne(vb.y) << 16);
        A.u[3] = bf16rne(vb.z) | (bf16rne(vb.w) << 16);

        #pragma unroll
        for (int nt = 0; nt < 4; ++nt) {
            int t = nt * 16 + li;
            unsigned byte = (unsigned)(t * 1024 + kk * 64 + g * 16)
                          ^ ((unsigned)(t & 7) << 4);
            bf16x8 B = *(const bf16x8*)(smem + byte);
            f32x4* accp = (nt == 0) ? &acc0 : (nt == 1) ? &acc1
                        : (nt == 2) ? &acc2 : &acc3;
            *accp = __builtin_amdgcn_mfma_f32_16x16x32_bf16(A.v, B, *accp, 0, 0, 0);
        }
    }
    __syncthreads();

    float* lg   = (float*)smem;
    float* redb = (float*)(smem + 64 * 65 * 4);
    float* gmax = redb + 256;

    #pragma unroll
    for (int nt = 0; nt < 4; ++nt) {
        const f32x4 a = (nt == 0) ? acc0 : (nt == 1) ? acc1
                      : (nt == 2) ? acc2 : acc3;
        int t = nt * 16 + li;
        #pragma unroll
        for (int q = 0; q < 4; ++q) {
            int rloc = w * 16 + g * 4 + q;
            int r = r0 + rloc;
            float v = -1e30f;
            if (r < L_) v = a[q] + b_out[r];
            lg[rloc * 65 + t] = v;
        }
    }
    __syncthreads();

    const int t = tid & 63, part = tid >> 6;
    float m = -1e30f;
    #pragma unroll
    for (int r16 = 0; r16 < 16; ++r16)
        m = fmaxf(m, lg[(part*16 + r16)*65 + t]);
    redb[part*64 + t] = m;
    __syncthreads();
    if (part == 0)
        gmax[t] = fmaxf(fmaxf(redb[t], redb[64+t]), fmaxf(redb[128+t], redb[192+t]));
    __syncthreads();
    float gm = gmax[t];
    float s = 0.f;
    #pragma unroll
    for (int r16 = 0; r16 < 16; ++r16)
        s += __expf(lg[(part*16 + r16)*65 + t] - gm);
    __syncthreads();
    redb[part*64 + t] = s;
    __syncthreads();
    if (part == 0) {
        pm[t * NBP_ + blockIdx.x] = gm;
        ps[t * NBP_ + blockIdx.x] = redb[t] + redb[64+t] + redb[128+t] + redb[192+t];
        int lb = labels[t];
        if (lb >= r0 && lb < r0 + 64) ll[t] = lg[(lb - r0)*65 + t];
    }
}

// ---------------- K5: combine partials, NLL, total loss ---------------------
__global__ __launch_bounds__(256) void k_final(
    const float* __restrict__ pm, const float* __restrict__ ps,
    const float* __restrict__ ll, const int* __restrict__ labels,
    float* __restrict__ out)
{
    __shared__ float rbuf[8];
    const int t = blockIdx.x, tid = threadIdx.x;
    float m = -1e30f;
    for (int b = tid; b < NB_; b += 256) m = fmaxf(m, pm[t * NBP_ + b]);
    for (int off = 32; off; off >>= 1) m = fmaxf(m, __shfl_down(m, off));
    if ((tid & 63) == 0) rbuf[tid >> 6] = m;
    __syncthreads();
    if (tid == 0) rbuf[4] = fmaxf(fmaxf(rbuf[0], rbuf[1]), fmaxf(rbuf[2], rbuf[3]));
    __syncthreads();
    float M = rbuf[4];
    __syncthreads();
    float s = 0.f;
    for (int b = tid; b < NB_; b += 256)
        s += ps[t * NBP_ + b] * __expf(pm[t * NBP_ + b] - M);
    for (int off = 32; off; off >>= 1) s += __shfl_down(s, off);
    if ((tid & 63) == 0) rbuf[tid >> 6] = s;
    __syncthreads();
    if (tid == 0) {
        float S = rbuf[0] + rbuf[1] + rbuf[2] + rbuf[3];
        int lb = labels[t];
        if (lb != 0) {
            float loss = -(ll[t] - M - __logf(S));
            atomicAdd(out, loss);
        }
    }
}

extern "C" void kernel_launch(void* const* d_in, const int* in_sizes, int n_in,
                              void* d_out, int out_size, void* d_ws, size_t ws_size,
                              hipStream_t stream)
{
    (void)in_sizes; (void)n_in; (void)out_size; (void)ws_size;
    const float* enc    = (const float*)d_in[0];
    const float* h0     = (const float*)d_in[1];
    const float* c0     = (const float*)d_in[2];
    const float* emb    = (const float*)d_in[3];
    const float* W_attn = (const float*)d_in[4];
    const float* b_attn = (const float*)d_in[5];
    const float* W_ih   = (const float*)d_in[6];
    const float* W_hh   = (const float*)d_in[7];
    const float* b_ih   = (const float*)d_in[8];
    const float* b_hh   = (const float*)d_in[9];
    const float* W_out  = (const float*)d_in[10];
    const float* b_out  = (const float*)d_in[11];
    const int* widx     = (const int*)d_in[12];
    const int* labels   = (const int*)d_in[13];
    float* out = (float*)d_out;

    char* ws = (char*)d_ws;
    float* ctx   = (float*)(ws + 0);          // 64*512*4      = 131072
    float* A_pre = (float*)(ws + 131072);     // 64*2048*4     = 524288
    float* h_buf = (float*)(ws + 655360);     // 64*512*4      = 131072
    float* pm    = (float*)(ws + 786688);     // 64*784*4      = 200704
    float* ps    = (float*)(ws + 987392);     // 64*784*4      = 200704
    float* ll    = (float*)(ws + 1188096);    // 64*4

    hipMemsetAsync(h_buf, 0xFF, T_ * H_ * sizeof(float), stream);  // sentinel
    hipMemsetAsync(out, 0, sizeof(float), stream);

    k_attn<<<T_, 256, 0, stream>>>(enc, emb, W_attn, b_attn, widx, ctx);
    k_gatepre<<<256, 256, 0, stream>>>(ctx, W_ih, b_ih, b_hh, A_pre);
    k_lstm<<<NWG_, 512, 0, stream>>>(W_hh, A_pre, h0, c0, h_buf);
    k_out<<<NB_, 256, 0, stream>>>(W_out, b_out, h_buf, labels, pm, ps, ll);
    k_final<<<T_, 256, 0, stream>>>(pm, ps, ll, labels, out);
}